// Round 2
// baseline (9.771 us; speedup 1.0000x reference)
//
#include <hip/hip_runtime.h>

// SmoothEmbedding: out[t,:] = w0*E[clip(i-1)] + w1*E[i] + w2*E[clip(i+1)],
// i = x[t]. The [N,N] banded smoothing matrix has only 3 nonzeros per row
// (taps, edge-clipped), so the [B,T,N]x[N,D] einsum collapses to a 3-row
// gather. We read the 3 tap values from interior row 1 of the f32 matrix
// so we match the stored weights exactly.
//
// Dtypes (evidence from round-1 failure): x=int32, embed_table=f32,
// smooth_weights=f32, out=f32. (Earlier bf16 guess read taps at the wrong
// byte offsets -> w=0 -> all-zero output.)

namespace {

constexpr int kNEmbed = 4096;
constexpr int kDim    = 128;

__global__ __launch_bounds__(256) void smooth_embed_kernel(
    const int*   __restrict__ x,
    const float* __restrict__ table,    // [N_EMBED, 128] f32
    const float* __restrict__ weights,  // [N_EMBED, N_EMBED] f32
    float*       __restrict__ out,      // [ntok, 128] f32
    int ntok)
{
    int tid   = blockIdx.x * blockDim.x + threadIdx.x;
    int token = tid >> 5;          // 32 threads per token
    if (token >= ntok) return;
    int d0    = (tid & 31) << 2;   // 4 floats per thread

    // Taps from interior row 1, cols 0..2: [0.15, 0.7, 0.15] as stored.
    float w0 = weights[(size_t)kNEmbed + 0];
    float w1 = weights[(size_t)kNEmbed + 1];
    float w2 = weights[(size_t)kNEmbed + 2];

    int i  = x[token];
    int im = i > 0 ? i - 1 : 0;
    int ip = i < kNEmbed - 1 ? i + 1 : kNEmbed - 1;

    const float4 a = *(const float4*)(table + (size_t)im * kDim + d0);
    const float4 b = *(const float4*)(table + (size_t)i  * kDim + d0);
    const float4 c = *(const float4*)(table + (size_t)ip * kDim + d0);

    float4 r;
    r.x = w0 * a.x + w1 * b.x + w2 * c.x;
    r.y = w0 * a.y + w1 * b.y + w2 * c.y;
    r.z = w0 * a.z + w1 * b.z + w2 * c.z;
    r.w = w0 * a.w + w1 * b.w + w2 * c.w;

    *(float4*)(out + (size_t)token * kDim + d0) = r;
}

} // namespace

extern "C" void kernel_launch(void* const* d_in, const int* in_sizes, int n_in,
                              void* d_out, int out_size, void* d_ws, size_t ws_size,
                              hipStream_t stream) {
    const int*   x       = (const int*)d_in[0];
    const float* table   = (const float*)d_in[1];
    const float* weights = (const float*)d_in[2];
    float*       out     = (float*)d_out;

    const int ntok    = in_sizes[0];          // B*T = 8192
    const int threads = ntok * 32;            // 32 threads per token (float4 each)
    const int block   = 256;
    const int grid    = (threads + block - 1) / block;

    smooth_embed_kernel<<<grid, block, 0, stream>>>(x, table, weights, out, ntok);
}